// Round 15
// baseline (64.154 us; speedup 1.0000x reference)
//
#include <hip/hip_runtime.h>
#include <math.h>

#define HW    64
#define NPIX  32768

typedef __attribute__((ext_vector_type(8))) short bf16x8;
typedef __attribute__((ext_vector_type(8))) short short8v;
typedef __attribute__((ext_vector_type(4))) float f32x4;

static __device__ inline short f2bf(float f) {
    union { float f; unsigned u; } v; v.f = f;
    unsigned r = v.u + 0x7fff + ((v.u >> 16) & 1);   // RNE
    return (short)(r >> 16);
}

// ---------------------------------------------------------------------------
// k_misc: blocks [0,512) transpose x NCHW f32 -> NHWC bf16, XCD-affine:
//         bid&7 = batch -> xt[b] stays in XCD b's L2.
//         blocks [512,728): wt3 lane-major main-weight frags + wc2 (proven).
// ---------------------------------------------------------------------------
__global__ __launch_bounds__(256) void k_misc(
        const float* __restrict__ x, short* __restrict__ xt,
        const float* __restrict__ w, const float* __restrict__ w_off,
        const float* __restrict__ w_mod,
        short* __restrict__ wt3, short* __restrict__ wc2) {
    int tid = threadIdx.x;
    if (blockIdx.x < 512) {
        __shared__ float s[64 * 65];
        int bid = blockIdx.x;
        int b = bid & 7, y = bid >> 3;               // XCD-affine remap
        const float* xb = x + ((size_t)b * 64) * 4096 + y * 64;
        #pragma unroll
        for (int q = 0; q < 4; ++q) {
            int fi = q * 256 + tid;
            int c = fi >> 4, xq = (fi & 15) * 4;
            float4 v = *(const float4*)(xb + (size_t)c * 4096 + xq);
            s[c * 65 + xq + 0] = v.x; s[c * 65 + xq + 1] = v.y;
            s[c * 65 + xq + 2] = v.z; s[c * 65 + xq + 3] = v.w;
        }
        __syncthreads();
        short* dst = xt + ((size_t)(b * 64 + y)) * 4096;
        #pragma unroll
        for (int q = 0; q < 4; ++q) {
            int fi = q * 256 + tid;
            int xx = fi >> 4, c = (fi & 15) * 4;
            short4 v = make_short4(f2bf(s[(c + 0) * 65 + xx]), f2bf(s[(c + 1) * 65 + xx]),
                                   f2bf(s[(c + 2) * 65 + xx]), f2bf(s[(c + 3) * 65 + xx]));
            *(short4*)(dst + xx * 64 + c) = v;
        }
    } else {
        int t = (blockIdx.x - 512) * 256 + tid;      // 0 .. 55295
        if (t < 36864) {
            int wv = t / 9216, r = t - wv * 9216;
            int f  = r >> 10;
            int r2 = r & 1023;
            int kk = r2 >> 9, lane = (r2 >> 3) & 63, j = r2 & 7;
            int o = wv * 16 + (lane & 15);
            int c = kk * 32 + (lane >> 4) * 8 + j;
            wt3[t] = f2bf(w[(o * 64 + c) * 9 + f]);
        }
        int u = t - 36864;
        if (u >= 0 && u < 9 * 32 * 64) {
            int c = u & 63, ch = (u >> 6) & 31, f = u >> 11;
            float v = 0.f;
            if (ch < 18)      v = w_off[(ch * 64 + c) * 9 + f];
            else if (ch < 27) v = w_mod[((ch - 18) * 64 + c) * 9 + f];
            wc2[u] = f2bf(v);
        }
    }
}

// ---------------------------------------------------------------------------
// k_convmetaG: per HALF-row (b,i,jb), 256 thr / 4 waves, grid 1024.
// XCD-affine: bid&7 = batch -> meta[b] and G[b] produced on XCD b, where
// k_final (also bid&7 = b) consumes them -> no cross-XCD dirty-line flush.
//  ph1: stage rows i-1..i+1 x cols jb-2..jb+33 (3x36 cells, swizzled)
//  ph2: offset/mask conv MFMA -> s_out[32ch][36]
//  ph3: bilinear meta -> global metaW/metaO (STRIDED)
//  ph4: G-GEMM from center staged row, direct bf16 stores via cvt_pk.
// ---------------------------------------------------------------------------
__global__ __launch_bounds__(256) void k_convmetaG(
        const short* __restrict__ xt,
        const short* __restrict__ wc2, const short* __restrict__ wt3,
        const float* __restrict__ b_off, const float* __restrict__ b_mod,
        float4* __restrict__ metaW, int4* __restrict__ metaO,
        short* __restrict__ G) {
    __shared__ __align__(16) char smem[18432];       // window 13824 + s_out 4608
    float* s_out = (float*)(smem + 13824);           // [32ch][36]

    int tid  = threadIdx.x;
    int lane = tid & 63;
    int wv   = __builtin_amdgcn_readfirstlane((int)(tid >> 6));
    int bid  = blockIdx.x;
    int blk  = (bid & 7) * 128 + (bid >> 3);         // XCD-affine remap
    int b = blk >> 7, i = (blk >> 1) & 63, jb = (blk & 1) * 32;
    int P0 = blk * 32;
    const short* xs = xt + (size_t)b * 262144;
    int arow = lane & 15, cg = lane >> 4, cgb = cg * 8;

    // ---- ph1: stage 3 rows x 36 cells (zero-padded), swizzled 16 B chunks
    for (int u = tid; u < 864; u += 256) {           // 108 cells x 8 chunks
        int cell = u >> 3, chunk = u & 7;
        int r = cell / 36, cc = cell - r * 36;
        int y = i - 1 + r, gx = jb + cc - 2;
        short8v v = (short8v){0,0,0,0,0,0,0,0};
        if (((unsigned)y < 64u) & ((unsigned)gx < 64u))
            v = *(const short8v*)(xs + ((y << 6) + gx) * 64 + chunk * 8);
        *(short8v*)(smem + cell * 128 + ((chunk * 16) ^ ((cell & 7) << 4))) = v;
    }
    __syncthreads();

    // ---- ph2: conv. wave (mh = px-half, nh = ch-half); M=32 px, N=32 ch.
    {
        int mh = wv & 1, nh = wv >> 1;
        f32x4 acc = (f32x4){0.f, 0.f, 0.f, 0.f};
        #pragma unroll
        for (int ky = 0; ky < 3; ++ky)
            #pragma unroll
            for (int kx = 0; kx < 3; ++kx) {
                int f = ky * 3 + kx;
                #pragma unroll
                for (int kk = 0; kk < 2; ++kk) {
                    bf16x8 bq = *(const bf16x8*)(wc2 + (f * 32 + nh * 16 + arow) * 64
                                                 + kk * 32 + cgb);
                    int cell = ky * 36 + mh * 16 + arow + kx + 1;
                    const char* ap = smem + cell * 128
                                   + ((kk * 64 + cg * 16) ^ ((cell & 7) << 4));
                    acc = __builtin_amdgcn_mfma_f32_16x16x32_bf16(
                        *(const bf16x8*)ap, bq, acc, 0, 0, 0);
                }
            }
        #pragma unroll
        for (int r = 0; r < 4; ++r)
            s_out[(nh * 16 + arow) * 36 + mh * 16 + cg * 4 + r] = acc[r];
    }
    __syncthreads();

    // ---- ph3: bilinear meta (288 = 9 taps x 32 px), STRIDED
    for (int u = tid; u < 288; u += 256) {
        int f = u >> 5, p = u & 31;
        float dy = s_out[(2 * f)     * 36 + p] + b_off[2 * f];
        float dx = s_out[(2 * f + 1) * 36 + p] + b_off[2 * f + 1];
        float mv = s_out[(18 + f)    * 36 + p] + b_mod[f];
        float m  = 1.f / (1.f + expf(-mv));

        float ys  = (float)(i - 1 + f / 3) + dy;
        float xs2 = (float)(jb + p - 1 + f % 3) + dx;
        float y0f = floorf(ys), x0f = floorf(xs2);
        int   y0  = (int)y0f,   x0  = (int)x0f;
        float fy = ys - y0f, fx = xs2 - x0f;

        bool vy0 = (unsigned)y0       < 64u, vy1 = (unsigned)(y0 + 1) < 64u;
        bool vx0 = (unsigned)x0       < 64u, vx1 = (unsigned)(x0 + 1) < 64u;
        float w00 = (vy0 & vx0) ? (1.f - fy) * (1.f - fx) * m : 0.f;
        float w01 = (vy0 & vx1) ? (1.f - fy) * fx         * m : 0.f;
        float w10 = (vy1 & vx0) ? fy         * (1.f - fx) * m : 0.f;
        float w11 = (vy1 & vx1) ? fy         * fx         * m : 0.f;

        int y0c = min(max(y0, 0), 63), y1c = min(max(y0 + 1, 0), 63);
        int x0c = min(max(x0, 0), 63), x1c = min(max(x0 + 1, 0), 63);

        metaW[f * NPIX + P0 + p] = make_float4(w00, w01, w10, w11);
        metaO[f * NPIX + P0 + p] = make_int4(((y0c << 6) + x0c) * 128,
                                             ((y0c << 6) + x1c) * 128,
                                             ((y1c << 6) + x0c) * 128,
                                             ((y1c << 6) + x1c) * 128);
    }

    // ---- ph4: G-GEMM from center row (window untouched since ph1 barrier)
    bf16x8 wfrag[9][2];
    #pragma unroll
    for (int f = 0; f < 9; ++f)
        #pragma unroll
        for (int kk = 0; kk < 2; ++kk)
            wfrag[f][kk] = *(const bf16x8*)(wt3 + ((wv * 18 + f * 2 + kk) * 64 + lane) * 8);

    #pragma unroll
    for (int f = 0; f < 9; ++f) {
        f32x4 g[2];
        g[0] = (f32x4){0.f, 0.f, 0.f, 0.f};
        g[1] = (f32x4){0.f, 0.f, 0.f, 0.f};
        #pragma unroll
        for (int kk = 0; kk < 2; ++kk)
            #pragma unroll
            for (int nf = 0; nf < 2; ++nf) {
                int cell = 36 + nf * 16 + arow + 2;  // center row, col jb+px
                const char* bp = smem + cell * 128
                               + ((kk * 64 + cg * 16) ^ ((cell & 7) << 4));
                g[nf] = __builtin_amdgcn_mfma_f32_16x16x32_bf16(
                    wfrag[f][kk], *(const bf16x8*)bp, g[nf], 0, 0, 0);
            }
        #pragma unroll
        for (int nf = 0; nf < 2; ++nf) {
            unsigned w0, w1;
            asm("v_cvt_pk_bf16_f32 %0, %1, %2" : "=v"(w0) : "v"(g[nf][0]), "v"(g[nf][1]));
            asm("v_cvt_pk_bf16_f32 %0, %1, %2" : "=v"(w1) : "v"(g[nf][2]), "v"(g[nf][3]));
            size_t base = (size_t)(f * NPIX + P0 + nf * 16 + arow) * 64 + wv * 16 + cg * 4;
            *(int2*)(G + base) = make_int2((int)w0, (int)w1);
        }
    }
}

// ---------------------------------------------------------------------------
// k_final: out[p][o] = bias[o] + sum_f sum_cn w[p,f,cn] * G_f[q(p,f,cn)][o].
// Grid 2048 (b = bid&7 -> same XCD as producer), 256 thr / 4 waves, 4 px/wave.
// Per px: batched load phase (18 corner loads in flight) then FMA phase.
// Paired-corner loads: lanes 0-31 corner A row, 32-63 corner B row, 4 B/lane;
// one __shfl_xor(32) reduce at the end.
// ---------------------------------------------------------------------------
__global__ __launch_bounds__(256, 4) void k_final(
        const short* __restrict__ G,
        const float4* __restrict__ metaW, const int4* __restrict__ metaO,
        const float* __restrict__ bias, float* __restrict__ out) {
    __shared__ float s_o[16][66];
    int tid  = threadIdx.x;
    int lane = tid & 63;
    int wv   = __builtin_amdgcn_readfirstlane((int)(tid >> 6));
    int bid  = blockIdx.x;
    int b = bid & 7, q = bid >> 3;                   // q in [0,256)
    int i = q >> 2, j0 = (q & 3) * 16;
    int P0 = b * 4096 + q * 16;
    int cp = lane & 31;
    bool hi = lane >= 32;
    const char* Gb = (const char*)G + (size_t)b * 524288;

    float aL[4], aH[4];
    #pragma unroll
    for (int k = 0; k < 4; ++k) { aL[k] = 0.f; aH[k] = 0.f; }

    #pragma unroll
    for (int pxi = 0; pxi < 4; ++pxi) {
        int P = P0 + wv * 4 + pxi;
        unsigned g0a[9], g1a[9];
        float wAa[9], wBa[9];
        #pragma unroll
        for (int f = 0; f < 9; ++f) {                // load phase: 18 in flight
            float4 mW = metaW[f * NPIX + P];         // wave-uniform -> s_load
            int4   mO = metaO[f * NPIX + P];
            const char* Gf = Gb + (size_t)f * 4194304;
            g0a[f] = *(const unsigned*)(Gf + (hi ? mO.y : mO.x) + cp * 4);
            g1a[f] = *(const unsigned*)(Gf + (hi ? mO.w : mO.z) + cp * 4);
            wAa[f] = hi ? mW.y : mW.x;
            wBa[f] = hi ? mW.w : mW.z;
        }
        float accL = 0.f, accH = 0.f;
        #pragma unroll
        for (int f = 0; f < 9; ++f) {                // FMA phase
            union { unsigned u; float f; } l0, h0, l1, h1;
            l0.u = g0a[f] << 16; h0.u = g0a[f] & 0xffff0000u;
            l1.u = g1a[f] << 16; h1.u = g1a[f] & 0xffff0000u;
            accL += wAa[f] * l0.f + wBa[f] * l1.f;
            accH += wAa[f] * h0.f + wBa[f] * h1.f;
        }
        aL[pxi] = accL; aH[pxi] = accH;
    }
    #pragma unroll
    for (int k = 0; k < 4; ++k) {
        aL[k] += __shfl_xor(aL[k], 32);
        aH[k] += __shfl_xor(aH[k], 32);
    }
    if (!hi) {
        #pragma unroll
        for (int k = 0; k < 4; ++k) {
            s_o[wv * 4 + k][2 * cp]     = aL[k];
            s_o[wv * 4 + k][2 * cp + 1] = aH[k];
        }
    }
    __syncthreads();
    {
        int o = tid >> 2, jq = tid & 3;
        float bv = bias[o];
        float4 v;
        v.x = s_o[jq * 4 + 0][o] + bv;
        v.y = s_o[jq * 4 + 1][o] + bv;
        v.z = s_o[jq * 4 + 2][o] + bv;
        v.w = s_o[jq * 4 + 3][o] + bv;
        *(float4*)(out + ((size_t)(b * 64 + o)) * 4096 + i * 64 + j0 + jq * 4) = v;
    }
}

// ---------------------------------------------------------------------------
extern "C" void kernel_launch(void* const* d_in, const int* in_sizes, int n_in,
                              void* d_out, int out_size, void* d_ws, size_t ws_size,
                              hipStream_t stream) {
    const float* x     = (const float*)d_in[0];
    const float* w_off = (const float*)d_in[1];
    const float* b_off = (const float*)d_in[2];
    const float* w_mod = (const float*)d_in[3];
    const float* b_mod = (const float*)d_in[4];
    const float* w     = (const float*)d_in[5];
    const float* bias  = (const float*)d_in[6];
    float* out = (float*)d_out;

    char* ws = (char*)d_ws;
    short*  xt    = (short*)(ws);                    //  4,194,304 B
    short*  wt3   = (short*)(ws + 4194304);          //     73,728 B
    short*  wc2   = (short*)(ws + 4268032);          //     36,864 B
    float4* metaW = (float4*)(ws + 4304896);         //  4,718,592 B
    int4*   metaO = (int4*)(ws + 9023488);           //  4,718,592 B
    short*  G     = (short*)(ws + 13742080);         // 37,748,736 B

    hipLaunchKernelGGL(k_misc,      dim3(728),  dim3(256), 0, stream,
                       x, xt, w, w_off, w_mod, wt3, wc2);
    hipLaunchKernelGGL(k_convmetaG, dim3(1024), dim3(256), 0, stream,
                       xt, wc2, wt3, b_off, b_mod, metaW, metaO, G);
    hipLaunchKernelGGL(k_final,     dim3(2048), dim3(256), 0, stream,
                       G, metaW, metaO, bias, out);
}